// Round 6
// baseline (462.291 us; speedup 1.0000x reference)
//
#include <hip/hip_runtime.h>
#include <hip/hip_bf16.h>

#define BATCH 256
#define TSTEPS 1024
#define NIN 128
#define NL 64
#define NH 128
#define NOUT 32

typedef __attribute__((ext_vector_type(8))) short short8;
typedef __attribute__((ext_vector_type(4))) float f32x4;

__device__ inline int pk2(float x, float y) {
    __hip_bfloat162 h = __float22bfloat162_rn(make_float2(x, y));
    union { __hip_bfloat162 h; int i; } u;
    u.h = h;
    return u.i;
}
__device__ inline short bf1(float x) {
    __hip_bfloat16 h = __float2bfloat16(x);
    union { __hip_bfloat16 h; short s; } u;
    u.h = h;
    return u.s;
}

// lgkmcnt drain + barrier; vmcnt (u-prefetch) stays in flight across it
#define WG_BARRIER() asm volatile("s_waitcnt lgkmcnt(0)\n\ts_barrier" ::: "memory")

// ---------------------------------------------------------------------------
// Pass 1: u'[t][b][l] = bf16( C[l,:]·s[b,t,:] + h1[l] )   (unchanged)
// ---------------------------------------------------------------------------
__launch_bounds__(256, 1)
__global__ void ugemm_mfma(const float* __restrict__ input,
                           const float* __restrict__ C,
                           const float* __restrict__ h1,
                           unsigned short* __restrict__ u16) {
    const int lane = threadIdx.x & 63;
    const int wv   = threadIdx.x >> 6;
    const int c = lane & 15;
    const int q = lane >> 4;
    const long wbase = ((long)blockIdx.x * 4 + wv) * 128;  // first row (b*1024+t)

    short8 cA[4][4];
    #pragma unroll
    for (int mt = 0; mt < 4; ++mt)
        #pragma unroll
        for (int kf = 0; kf < 4; ++kf) {
            const float* p = C + (mt * 16 + c) * NIN + kf * 32 + q * 8;
            float4 r0 = *(const float4*)p;
            float4 r1 = *(const float4*)(p + 4);
            union { short8 s; int i[4]; } f;
            f.i[0] = pk2(r0.x, r0.y); f.i[1] = pk2(r0.z, r0.w);
            f.i[2] = pk2(r1.x, r1.y); f.i[3] = pk2(r1.z, r1.w);
            cA[mt][kf] = f.s;
        }
    f32x4 h1f[4];
    #pragma unroll
    for (int mt = 0; mt < 4; ++mt)
        h1f[mt] = *(const f32x4*)(h1 + mt * 16 + q * 4);

    float4 raw[8], rawn[8];
    {
        const float* sr = input + (wbase + c) * NIN;
        #pragma unroll
        for (int kf = 0; kf < 4; ++kf) {
            raw[2*kf]   = *(const float4*)(sr + kf * 32 + q * 8);
            raw[2*kf+1] = *(const float4*)(sr + kf * 32 + q * 8 + 4);
        }
    }

    for (int it = 0; it < 8; ++it) {
        if (it < 7) {
            const float* sr = input + (wbase + (it + 1) * 16 + c) * NIN;
            #pragma unroll
            for (int kf = 0; kf < 4; ++kf) {
                rawn[2*kf]   = *(const float4*)(sr + kf * 32 + q * 8);
                rawn[2*kf+1] = *(const float4*)(sr + kf * 32 + q * 8 + 4);
            }
        }
        short8 bf[4];
        #pragma unroll
        for (int kf = 0; kf < 4; ++kf) {
            union { short8 s; int i[4]; } f;
            f.i[0] = pk2(raw[2*kf].x,   raw[2*kf].y);
            f.i[1] = pk2(raw[2*kf].z,   raw[2*kf].w);
            f.i[2] = pk2(raw[2*kf+1].x, raw[2*kf+1].y);
            f.i[3] = pk2(raw[2*kf+1].z, raw[2*kf+1].w);
            bf[kf] = f.s;
        }
        long rr = wbase + it * 16 + c;
        int b = (int)(rr >> 10), t = (int)(rr & 1023);
        unsigned short* ubase = u16 + ((size_t)t * 256 + b) * 64 + q * 4;
        #pragma unroll
        for (int mt = 0; mt < 4; ++mt) {
            f32x4 acc = __builtin_amdgcn_mfma_f32_16x16x32_bf16(cA[mt][0], bf[0], h1f[mt], 0, 0, 0);
            acc = __builtin_amdgcn_mfma_f32_16x16x32_bf16(cA[mt][1], bf[1], acc, 0, 0, 0);
            acc = __builtin_amdgcn_mfma_f32_16x16x32_bf16(cA[mt][2], bf[2], acc, 0, 0, 0);
            acc = __builtin_amdgcn_mfma_f32_16x16x32_bf16(cA[mt][3], bf[3], acc, 0, 0, 0);
            *(int2*)(ubase + mt * 16) =
                make_int2(pk2(acc[0], acc[1]), pk2(acc[2], acc[3]));
        }
        #pragma unroll
        for (int j = 0; j < 8; ++j) raw[j] = rawn[j];
    }
}

// ---------------------------------------------------------------------------
// Pass 2: champion structure (4-wave M-split, 2 barriers/step) with cin
// moved into the bz-read latency shadow:
//   publish z | barrier | read bz ; [cin = A*z + u(T) ; prefetch u(T+2)]
//   GEMM1 | relu/pack/publish H | barrier | read bh | GEMM2(cin) | clip
// The A*z+u tail is no longer between GEMM2 and the z-publish.
// Grid 16 WGs x 256 thr; wave w: H tiles {2w,2w+1}, z tile w.
// ---------------------------------------------------------------------------
__launch_bounds__(256, 1)
__global__ void plrnn_scan_mfma(const float* __restrict__ A,
                                const float* __restrict__ W1,
                                const float* __restrict__ W2,
                                const float* __restrict__ h2,
                                const unsigned short* __restrict__ u16,
                                const float* __restrict__ Wout,
                                const float* __restrict__ bout,
                                float* __restrict__ out) {
    __shared__ __attribute__((aligned(16))) unsigned short zbuf[16 * 72];
    __shared__ __attribute__((aligned(16))) unsigned short hbuf[16 * 136];

    const int lane = threadIdx.x & 63;
    const int w    = threadIdx.x >> 6;     // wave 0..3
    const int c = lane & 15;               // batch col
    const int q = lane >> 4;               // quad
    const int bbase = blockIdx.x * 16;

    // ---- static weight fragments ----
    short8 aw2[2][2];   // H tiles mt = 2w, 2w+1 ; K = 64 (2 frags)
    #pragma unroll
    for (int i = 0; i < 2; ++i)
        #pragma unroll
        for (int kt = 0; kt < 2; ++kt) {
            const float* p = W2 + ((2*w + i) * 16 + c) * NL + kt * 32 + q * 8;
            short8 f;
            #pragma unroll
            for (int j = 0; j < 8; ++j) f[j] = bf1(p[j]);
            aw2[i][kt] = f;
        }
    short8 aw1[4];      // Z tile lt = w ; K = 128 (4 frags)
    #pragma unroll
    for (int kt = 0; kt < 4; ++kt) {
        const float* p = W1 + (w * 16 + c) * NH + kt * 32 + q * 8;
        short8 f;
        #pragma unroll
        for (int j = 0; j < 8; ++j) f[j] = bf1(p[j]);
        aw1[kt] = f;
    }
    f32x4 h2f[2];
    #pragma unroll
    for (int i = 0; i < 2; ++i)
        h2f[i] = *(const f32x4*)(h2 + (2*w + i) * 16 + q * 4);
    const f32x4 af = *(const f32x4*)(A + w * 16 + q * 4);
    const f32x4 zero4 = {0.f, 0.f, 0.f, 0.f};

    // u' stream: index (t*256 + bbase+c)*64 + w*16 + q*4 ; stride/t = 16384
    const unsigned short* ub = u16 + ((size_t)(bbase + c)) * 64 + w * 16 + q * 4;
    int2 uP = *(const int2*)ub;                // u(0)
    int2 uQ = *(const int2*)(ub + 16384);      // u(1)

    f32x4 zf = {0.f, 0.f, 0.f, 0.f};           // z(0) = 0

    // one timestep: ubuf holds u(T) on entry; u(T+2) prefetched into it after
    // cin consumes it (2-step flight time covers HBM/L2 latency).
    auto step = [&](int2& ubuf, const int T) {
        // ---- publish z(T) (wave w owns latents [16w,16w+16)) ----
        *(int2*)&zbuf[c * 72 + w * 16 + q * 4] =
            make_int2(pk2(zf[0], zf[1]), pk2(zf[2], zf[3]));
        WG_BARRIER();
        short8 bz0 = *(short8*)&zbuf[c * 72 + q * 8];
        short8 bz1 = *(short8*)&zbuf[c * 72 + 32 + q * 8];

        // ---- read-latency shadow: cin = A*z(T) + u(T), then prefetch ----
        f32x4 cin;
        cin[0] = fmaf(zf[0], af[0], __int_as_float(ubuf.x << 16));
        cin[1] = fmaf(zf[1], af[1], __int_as_float(ubuf.x & 0xffff0000));
        cin[2] = fmaf(zf[2], af[2], __int_as_float(ubuf.y << 16));
        cin[3] = fmaf(zf[3], af[3], __int_as_float(ubuf.y & 0xffff0000));
        const int tp = (T + 2 < TSTEPS) ? T + 2 : TSTEPS - 1;
        ubuf = *(const int2*)(ub + (size_t)tp * 16384);   // u(T+2), in flight

        // ---- MFMA1: H rows [32w,32w+32) = relu(W2 @ Z + h2) ----
        #pragma unroll
        for (int i = 0; i < 2; ++i) {
            f32x4 acc = __builtin_amdgcn_mfma_f32_16x16x32_bf16(aw2[i][0], bz0, h2f[i], 0, 0, 0);
            acc = __builtin_amdgcn_mfma_f32_16x16x32_bf16(aw2[i][1], bz1, acc, 0, 0, 0);
            *(int2*)&hbuf[c * 136 + (2*w + i) * 16 + q * 4] =
                make_int2(pk2(fmaxf(acc[0], 0.f), fmaxf(acc[1], 0.f)),
                          pk2(fmaxf(acc[2], 0.f), fmaxf(acc[3], 0.f)));
        }
        WG_BARRIER();
        short8 bh0 = *(short8*)&hbuf[c * 136 + q * 8];
        short8 bh1 = *(short8*)&hbuf[c * 136 + 32 + q * 8];
        short8 bh2 = *(short8*)&hbuf[c * 136 + 64 + q * 8];
        short8 bh3 = *(short8*)&hbuf[c * 136 + 96 + q * 8];

        // ---- MFMA2: Z' rows [16w,16w+16), two depth-2 chains + add ----
        f32x4 acc_a = __builtin_amdgcn_mfma_f32_16x16x32_bf16(aw1[0], bh0, cin, 0, 0, 0);
        acc_a = __builtin_amdgcn_mfma_f32_16x16x32_bf16(aw1[1], bh1, acc_a, 0, 0, 0);
        f32x4 acc_b = __builtin_amdgcn_mfma_f32_16x16x32_bf16(aw1[2], bh2, zero4, 0, 0, 0);
        acc_b = __builtin_amdgcn_mfma_f32_16x16x32_bf16(aw1[3], bh3, acc_b, 0, 0, 0);

        #pragma unroll
        for (int e = 0; e < 4; ++e)
            zf[e] = __builtin_amdgcn_fmed3f(acc_a[e] + acc_b[e], -5.f, 5.f);
    };

    for (int t = 0; t < TSTEPS; t += 2) {
        step(uP, t);       // uses u(t)   from uP, prefetches u(t+2) into uP
        step(uQ, t + 1);   // uses u(t+1) from uQ, prefetches u(t+3) into uQ
    }

    // ---- epilogue: out = Wout @ z(T) + bout (waves 0,1) ----
    *(int2*)&zbuf[c * 72 + w * 16 + q * 4] =
        make_int2(pk2(zf[0], zf[1]), pk2(zf[2], zf[3]));
    WG_BARRIER();
    if (w < 2) {
        short8 fz0 = *(short8*)&zbuf[c * 72 + q * 8];
        short8 fz1 = *(short8*)&zbuf[c * 72 + 32 + q * 8];
        const float* p0 = Wout + (w * 16 + c) * NL + q * 8;
        const float* p1 = p0 + 32;
        short8 fa, fb;
        #pragma unroll
        for (int j = 0; j < 8; ++j) { fa[j] = bf1(p0[j]); fb[j] = bf1(p1[j]); }
        f32x4 cb = *(const f32x4*)(bout + w * 16 + q * 4);
        f32x4 acc = __builtin_amdgcn_mfma_f32_16x16x32_bf16(fa, fz0, cb, 0, 0, 0);
        acc = __builtin_amdgcn_mfma_f32_16x16x32_bf16(fb, fz1, acc, 0, 0, 0);
        *(f32x4*)&out[(bbase + c) * 32 + w * 16 + q * 4] = acc;
    }
}

extern "C" void kernel_launch(void* const* d_in, const int* in_sizes, int n_in,
                              void* d_out, int out_size, void* d_ws, size_t ws_size,
                              hipStream_t stream) {
    const float* input = (const float*)d_in[0];
    const float* A     = (const float*)d_in[1];
    const float* W1    = (const float*)d_in[2];
    const float* W2    = (const float*)d_in[3];
    const float* h1    = (const float*)d_in[4];
    const float* h2    = (const float*)d_in[5];
    const float* C     = (const float*)d_in[6];
    const float* Wout  = (const float*)d_in[7];
    const float* bout  = (const float*)d_in[8];
    float* out = (float*)d_out;

    unsigned short* u16 = (unsigned short*)d_ws;   // 256*1024*64 bf16 = 33.5 MB

    ugemm_mfma<<<dim3(512), dim3(256), 0, stream>>>(input, C, h1, u16);
    plrnn_scan_mfma<<<dim3(16), dim3(256), 0, stream>>>(
        A, W1, W2, h2, u16, Wout, bout, out);
}

// Round 7
// 449.376 us; speedup vs baseline: 1.0287x; 1.0287x over previous
//
#include <hip/hip_runtime.h>
#include <hip/hip_bf16.h>

#define BATCH 256
#define TSTEPS 1024
#define NIN 128
#define NL 64
#define NH 128
#define NOUT 32

typedef __attribute__((ext_vector_type(8))) short short8;
typedef __attribute__((ext_vector_type(4))) float f32x4;

__device__ inline int pk2(float x, float y) {
    __hip_bfloat162 h = __float22bfloat162_rn(make_float2(x, y));
    union { __hip_bfloat162 h; int i; } u;
    u.h = h;
    return u.i;
}
__device__ inline short bf1(float x) {
    __hip_bfloat16 h = __float2bfloat16(x);
    union { __hip_bfloat16 h; short s; } u;
    u.h = h;
    return u.s;
}

// lgkmcnt drain + barrier; vmcnt (u-prefetch) stays in flight across it
#define WG_BARRIER() asm volatile("s_waitcnt lgkmcnt(0)\n\ts_barrier" ::: "memory")

// ---------------------------------------------------------------------------
// Pass 1: u'[t][b][l] = bf16( C[l,:]·s[b,t,:] + h1[l] )
// ---------------------------------------------------------------------------
__launch_bounds__(256, 1)
__global__ void ugemm_mfma(const float* __restrict__ input,
                           const float* __restrict__ C,
                           const float* __restrict__ h1,
                           unsigned short* __restrict__ u16) {
    const int lane = threadIdx.x & 63;
    const int wv   = threadIdx.x >> 6;
    const int c = lane & 15;
    const int q = lane >> 4;
    const long wbase = ((long)blockIdx.x * 4 + wv) * 128;  // first row (b*1024+t)

    short8 cA[4][4];
    #pragma unroll
    for (int mt = 0; mt < 4; ++mt)
        #pragma unroll
        for (int kf = 0; kf < 4; ++kf) {
            const float* p = C + (mt * 16 + c) * NIN + kf * 32 + q * 8;
            float4 r0 = *(const float4*)p;
            float4 r1 = *(const float4*)(p + 4);
            union { short8 s; int i[4]; } f;
            f.i[0] = pk2(r0.x, r0.y); f.i[1] = pk2(r0.z, r0.w);
            f.i[2] = pk2(r1.x, r1.y); f.i[3] = pk2(r1.z, r1.w);
            cA[mt][kf] = f.s;
        }
    f32x4 h1f[4];
    #pragma unroll
    for (int mt = 0; mt < 4; ++mt)
        h1f[mt] = *(const f32x4*)(h1 + mt * 16 + q * 4);

    float4 raw[8], rawn[8];
    {
        const float* sr = input + (wbase + c) * NIN;
        #pragma unroll
        for (int kf = 0; kf < 4; ++kf) {
            raw[2*kf]   = *(const float4*)(sr + kf * 32 + q * 8);
            raw[2*kf+1] = *(const float4*)(sr + kf * 32 + q * 8 + 4);
        }
    }

    for (int it = 0; it < 8; ++it) {
        if (it < 7) {
            const float* sr = input + (wbase + (it + 1) * 16 + c) * NIN;
            #pragma unroll
            for (int kf = 0; kf < 4; ++kf) {
                rawn[2*kf]   = *(const float4*)(sr + kf * 32 + q * 8);
                rawn[2*kf+1] = *(const float4*)(sr + kf * 32 + q * 8 + 4);
            }
        }
        short8 bf[4];
        #pragma unroll
        for (int kf = 0; kf < 4; ++kf) {
            union { short8 s; int i[4]; } f;
            f.i[0] = pk2(raw[2*kf].x,   raw[2*kf].y);
            f.i[1] = pk2(raw[2*kf].z,   raw[2*kf].w);
            f.i[2] = pk2(raw[2*kf+1].x, raw[2*kf+1].y);
            f.i[3] = pk2(raw[2*kf+1].z, raw[2*kf+1].w);
            bf[kf] = f.s;
        }
        long rr = wbase + it * 16 + c;
        int b = (int)(rr >> 10), t = (int)(rr & 1023);
        unsigned short* ubase = u16 + ((size_t)t * 256 + b) * 64 + q * 4;
        #pragma unroll
        for (int mt = 0; mt < 4; ++mt) {
            f32x4 acc = __builtin_amdgcn_mfma_f32_16x16x32_bf16(cA[mt][0], bf[0], h1f[mt], 0, 0, 0);
            acc = __builtin_amdgcn_mfma_f32_16x16x32_bf16(cA[mt][1], bf[1], acc, 0, 0, 0);
            acc = __builtin_amdgcn_mfma_f32_16x16x32_bf16(cA[mt][2], bf[2], acc, 0, 0, 0);
            acc = __builtin_amdgcn_mfma_f32_16x16x32_bf16(cA[mt][3], bf[3], acc, 0, 0, 0);
            *(int2*)(ubase + mt * 16) =
                make_int2(pk2(acc[0], acc[1]), pk2(acc[2], acc[3]));
        }
        #pragma unroll
        for (int j = 0; j < 8; ++j) raw[j] = rawn[j];
    }
}

// ---------------------------------------------------------------------------
// Pass 2: champion structure (4-wave M-split, 2 barriers/step) + polish:
//  - zero-copy pf/tail u-prefetch rotation (cin computed at step end)
//  - fmed3 clip
//  - MFMA2 as two depth-2 accumulator chains + add (latency hedge)
// Grid 16 WGs x 256 thr; WG = 16 batches. Wave w: H tiles {2w,2w+1},
// z tile w.  Measured floor: ~975 cy/step = 8 solo-wave MFMA x ~46 cy
// + 2 cross-wave exchanges x ~280 cy + ~100 cy VALU tail.
// ---------------------------------------------------------------------------
__launch_bounds__(256, 1)
__global__ void plrnn_scan_mfma(const float* __restrict__ A,
                                const float* __restrict__ W1,
                                const float* __restrict__ W2,
                                const float* __restrict__ h2,
                                const unsigned short* __restrict__ u16,
                                const float* __restrict__ Wout,
                                const float* __restrict__ bout,
                                float* __restrict__ out) {
    __shared__ __attribute__((aligned(16))) unsigned short zbuf[16 * 72];
    __shared__ __attribute__((aligned(16))) unsigned short hbuf[16 * 136];

    const int lane = threadIdx.x & 63;
    const int w    = threadIdx.x >> 6;     // wave 0..3
    const int c = lane & 15;               // batch col
    const int q = lane >> 4;               // quad
    const int bbase = blockIdx.x * 16;

    // ---- static weight fragments ----
    short8 aw2[2][2];   // H tiles mt = 2w, 2w+1 ; K = 64 (2 frags)
    #pragma unroll
    for (int i = 0; i < 2; ++i)
        #pragma unroll
        for (int kt = 0; kt < 2; ++kt) {
            const float* p = W2 + ((2*w + i) * 16 + c) * NL + kt * 32 + q * 8;
            short8 f;
            #pragma unroll
            for (int j = 0; j < 8; ++j) f[j] = bf1(p[j]);
            aw2[i][kt] = f;
        }
    short8 aw1[4];      // Z tile lt = w ; K = 128 (4 frags)
    #pragma unroll
    for (int kt = 0; kt < 4; ++kt) {
        const float* p = W1 + (w * 16 + c) * NH + kt * 32 + q * 8;
        short8 f;
        #pragma unroll
        for (int j = 0; j < 8; ++j) f[j] = bf1(p[j]);
        aw1[kt] = f;
    }
    f32x4 h2f[2];
    #pragma unroll
    for (int i = 0; i < 2; ++i)
        h2f[i] = *(const f32x4*)(h2 + (2*w + i) * 16 + q * 4);
    const f32x4 af = *(const f32x4*)(A + w * 16 + q * 4);
    const f32x4 zero4 = {0.f, 0.f, 0.f, 0.f};

    // u' stream: index (t*256 + bbase+c)*64 + w*16 + q*4 ; stride/t = 16384
    const unsigned short* ub = u16 + ((size_t)(bbase + c)) * 64 + w * 16 + q * 4;
    int2 uP = *(const int2*)ub;                // u(0)
    int2 uQ = *(const int2*)(ub + 16384);      // u(1)

    f32x4 zf = {0.f, 0.f, 0.f, 0.f};

    // cin(t=0) = u(0)   (A*z0 = 0)
    f32x4 cin;
    cin[0] = __int_as_float(uP.x << 16);
    cin[1] = __int_as_float(uP.x & 0xffff0000);
    cin[2] = __int_as_float(uP.y << 16);
    cin[3] = __int_as_float(uP.y & 0xffff0000);

    // one timestep; pf <- prefetch target (u(T+2)), tail <- u(T+1) for next cin
    auto step = [&](int2& pf, const int2& tail, const int T) {
        // ---- publish z (wave w owns latents [16w,16w+16)) ----
        *(int2*)&zbuf[c * 72 + w * 16 + q * 4] =
            make_int2(pk2(zf[0], zf[1]), pk2(zf[2], zf[3]));
        WG_BARRIER();
        short8 bz0 = *(short8*)&zbuf[c * 72 + q * 8];
        short8 bz1 = *(short8*)&zbuf[c * 72 + 32 + q * 8];

        // prefetch u'(T+2) — stays in flight across both MFMA phases
        const int tp = (T + 2 < TSTEPS) ? T + 2 : TSTEPS - 1;
        pf = *(const int2*)(ub + (size_t)tp * 16384);

        // ---- MFMA1: H rows [32w,32w+32) = relu(W2 @ Z + h2) ----
        #pragma unroll
        for (int i = 0; i < 2; ++i) {
            f32x4 acc = __builtin_amdgcn_mfma_f32_16x16x32_bf16(aw2[i][0], bz0, h2f[i], 0, 0, 0);
            acc = __builtin_amdgcn_mfma_f32_16x16x32_bf16(aw2[i][1], bz1, acc, 0, 0, 0);
            *(int2*)&hbuf[c * 136 + (2*w + i) * 16 + q * 4] =
                make_int2(pk2(fmaxf(acc[0], 0.f), fmaxf(acc[1], 0.f)),
                          pk2(fmaxf(acc[2], 0.f), fmaxf(acc[3], 0.f)));
        }
        WG_BARRIER();
        short8 bh0 = *(short8*)&hbuf[c * 136 + q * 8];
        short8 bh1 = *(short8*)&hbuf[c * 136 + 32 + q * 8];
        short8 bh2 = *(short8*)&hbuf[c * 136 + 64 + q * 8];
        short8 bh3 = *(short8*)&hbuf[c * 136 + 96 + q * 8];

        // ---- MFMA2: Z' rows [16w,16w+16), two depth-2 chains + add ----
        f32x4 acc_a = __builtin_amdgcn_mfma_f32_16x16x32_bf16(aw1[0], bh0, cin, 0, 0, 0);
        acc_a = __builtin_amdgcn_mfma_f32_16x16x32_bf16(aw1[1], bh1, acc_a, 0, 0, 0);
        f32x4 acc_b = __builtin_amdgcn_mfma_f32_16x16x32_bf16(aw1[2], bh2, zero4, 0, 0, 0);
        acc_b = __builtin_amdgcn_mfma_f32_16x16x32_bf16(aw1[3], bh3, acc_b, 0, 0, 0);

        #pragma unroll
        for (int e = 0; e < 4; ++e)
            zf[e] = __builtin_amdgcn_fmed3f(acc_a[e] + acc_b[e], -5.f, 5.f);

        // next cin = A*z' + u(T+1)
        cin[0] = fmaf(zf[0], af[0], __int_as_float(tail.x << 16));
        cin[1] = fmaf(zf[1], af[1], __int_as_float(tail.x & 0xffff0000));
        cin[2] = fmaf(zf[2], af[2], __int_as_float(tail.y << 16));
        cin[3] = fmaf(zf[3], af[3], __int_as_float(tail.y & 0xffff0000));
    };

    for (int t = 0; t < TSTEPS; t += 2) {
        step(uP, uQ, t);       // even: prefetch->uP, tail uses uQ = u(t+1)
        step(uQ, uP, t + 1);   // odd:  prefetch->uQ, tail uses uP = u(t+2)
    }

    // ---- epilogue: out = Wout @ Z + bout (waves 0,1) ----
    *(int2*)&zbuf[c * 72 + w * 16 + q * 4] =
        make_int2(pk2(zf[0], zf[1]), pk2(zf[2], zf[3]));
    WG_BARRIER();
    if (w < 2) {
        short8 fz0 = *(short8*)&zbuf[c * 72 + q * 8];
        short8 fz1 = *(short8*)&zbuf[c * 72 + 32 + q * 8];
        const float* p0 = Wout + (w * 16 + c) * NL + q * 8;
        const float* p1 = p0 + 32;
        short8 fa, fb;
        #pragma unroll
        for (int j = 0; j < 8; ++j) { fa[j] = bf1(p0[j]); fb[j] = bf1(p1[j]); }
        f32x4 cb = *(const f32x4*)(bout + w * 16 + q * 4);
        f32x4 acc = __builtin_amdgcn_mfma_f32_16x16x32_bf16(fa, fz0, cb, 0, 0, 0);
        acc = __builtin_amdgcn_mfma_f32_16x16x32_bf16(fb, fz1, acc, 0, 0, 0);
        *(f32x4*)&out[(bbase + c) * 32 + w * 16 + q * 4] = acc;
    }
}

extern "C" void kernel_launch(void* const* d_in, const int* in_sizes, int n_in,
                              void* d_out, int out_size, void* d_ws, size_t ws_size,
                              hipStream_t stream) {
    const float* input = (const float*)d_in[0];
    const float* A     = (const float*)d_in[1];
    const float* W1    = (const float*)d_in[2];
    const float* W2    = (const float*)d_in[3];
    const float* h1    = (const float*)d_in[4];
    const float* h2    = (const float*)d_in[5];
    const float* C     = (const float*)d_in[6];
    const float* Wout  = (const float*)d_in[7];
    const float* bout  = (const float*)d_in[8];
    float* out = (float*)d_out;

    unsigned short* u16 = (unsigned short*)d_ws;   // 256*1024*64 bf16 = 33.5 MB

    ugemm_mfma<<<dim3(512), dim3(256), 0, stream>>>(input, C, h1, u16);
    plrnn_scan_mfma<<<dim3(16), dim3(256), 0, stream>>>(
        A, W1, W2, h2, u16, Wout, bout, out);
}